// Round 15
// baseline (327.075 us; speedup 1.0000x reference)
//
#include <hip/hip_runtime.h>

#define NN 20000
#define NE 320000
#define NB 64
#define BNG 128  // bnstats partial-sum blocks

typedef __attribute__((ext_vector_type(4))) float f32x4;
typedef __attribute__((ext_vector_type(8))) __bf16 bf16x8;

static __device__ __forceinline__ ushort f2bf(float f) {
    uint u = __builtin_bit_cast(uint, f);
    uint r = (u + 0x7fffu + ((u >> 16) & 1u)) >> 16;
    return (ushort)r;
}
static __device__ __forceinline__ float bf2f(ushort u) {
    return __builtin_bit_cast(float, (uint)u << 16);
}

#define GLD_LDS16(g, l)                                                                     \
    __builtin_amdgcn_global_load_lds((__attribute__((address_space(1))) void*)(g),          \
                                     (__attribute__((address_space(3))) void*)(l), 16, 0, 0)

struct WtJob { const float* root; const float* rel; ushort* dst; int K; int C; };
struct FillArgs { const int* ei_t; const int* et_t; const int* ei_p; const int* et_p;
                  const int* off; const int* posArr; int* adj; };

// ---------------- fused prep: countpos ∥ cast_x ∥ cast_wt ----------

__global__ __launch_bounds__(256) void k_prep(const int* __restrict__ ei_t, const int* __restrict__ ei_p,
                                              int* __restrict__ deg, int* __restrict__ posArr,
                                              const float* __restrict__ xt, const float* __restrict__ xp,
                                              ushort* __restrict__ ot, ushort* __restrict__ op,
                                              int n4t, int n4p,
                                              WtJob j0, WtJob j1, WtJob j2, WtJob j3,
                                              int c1, int c2, int c3, int nbCount, int nbCast) {
    __shared__ float tile[32][33];
    int bid = blockIdx.x;
    int tid = threadIdx.x;
    if (bid < nbCount) {
        int e = bid * 256 + tid;
        if (e >= 2 * NE) return;
        int br = e >= NE;
        int el = e - br * NE;
        const int* ei = br ? ei_p : ei_t;
        int dst = ei[NE + el];
        posArr[e] = atomicAdd(&deg[br * NN + dst], 1);
        return;
    }
    if (bid < nbCount + nbCast) {
        int i = (bid - nbCount) * 256 + tid;
        const float* in; ushort* out; int j;
        if (i < n4t) { in = xt; out = ot; j = i; }
        else { j = i - n4t; if (j >= n4p) return; in = xp; out = op; }
        float4 v = *(const float4*)&in[(size_t)j * 4];
        ushort4 o;
        o.x = f2bf(v.x); o.y = f2bf(v.y); o.z = f2bf(v.z); o.w = f2bf(v.w);
        *(ushort4*)&out[(size_t)j * 4] = o;
        return;
    }
    int lt0 = bid - nbCount - nbCast;
    WtJob j; int lt;
    if (lt0 < c1) { j = j0; lt = lt0; }
    else if (lt0 < c2) { j = j1; lt = lt0 - c1; }
    else if (lt0 < c3) { j = j2; lt = lt0 - c2; }
    else { j = j3; lt = lt0 - c3; }
    int nx = j.K >> 5, ny = j.C >> 5;
    int mat = lt / (nx * ny);
    int r2 = lt - mat * (nx * ny);
    int kx = r2 % nx, cy = r2 / nx;
    int KC = j.K * j.C;
    const float* W = (mat == 0) ? j.root : j.rel + (size_t)(mat - 1) * KC;
    int k0 = kx * 32, c0 = cy * 32;
    int tx = tid & 31, ty = tid >> 5;
#pragma unroll
    for (int i = 0; i < 4; i++)
        tile[ty + i * 8][tx] = W[(size_t)(k0 + ty + i * 8) * j.C + c0 + tx];
    __syncthreads();
#pragma unroll
    for (int i = 0; i < 4; i++)
        j.dst[(size_t)mat * KC + (size_t)(c0 + ty + i * 8) * j.K + k0 + tx] = f2bf(tile[tx][ty + i * 8]);
}

// ---------------- scans ----------------

__global__ __launch_bounds__(256) void k_scan_local(const int* __restrict__ deg, int* __restrict__ off,
                                                    int* __restrict__ csum, int n) {
    __shared__ int sh[256];
    int base = blockIdx.x * 256, tid = threadIdx.x;
    int v = (base + tid < n) ? deg[base + tid] : 0;
    sh[tid] = v; __syncthreads();
    for (int o = 1; o < 256; o <<= 1) {
        int t = (tid >= o) ? sh[tid - o] : 0;
        __syncthreads();
        sh[tid] += t;
        __syncthreads();
    }
    if (base + tid < n) off[base + tid] = sh[tid] - v;  // exclusive
    if (tid == 255) csum[blockIdx.x] = sh[255];
}

__global__ void k_scan_csum(int* __restrict__ csum, int* __restrict__ offN, int nc) {
    __shared__ int sh[256];
    int tid = threadIdx.x;
    int v = (tid < nc) ? csum[tid] : 0;
    sh[tid] = v; __syncthreads();
    for (int o = 1; o < 256; o <<= 1) {
        int t = (tid >= o) ? sh[tid - o] : 0;
        __syncthreads();
        sh[tid] += t;
        __syncthreads();
    }
    if (tid < nc) csum[tid] = sh[tid] - v;  // exclusive
    if (tid == 255) offN[0] = sh[255];
}

__global__ __launch_bounds__(256) void k_scan_add(int* __restrict__ off, const int* __restrict__ csum, int n) {
    int i = blockIdx.x * 256 + threadIdx.x;
    if (i < n) off[i] += csum[blockIdx.x];
}

// ---------------- MFMA GEMM: 128x128 z-split tile, A via LDS, B DIRECT from global (L2) ----
// LDS 32KB (A-stage 16KB inside epilogue bounce buffer). launch_bounds(256,4) -> VGPR<=128,
// 4 blocks/CU. fillpos fused as extra blocks.

struct GemmJob { const ushort* A; const ushort* Wt; const float* bias;
                 ushort* root; ushort* h0; ushort* h1; int K; };

__global__ __launch_bounds__(256, 4) void k_gemm_fill(GemmJob j0, GemmJob j1, int M, int C, int NBR,
                                                      int nwgG, FillArgs fa) {
    __shared__ ushort smem[16384];  // 32 KB

    if ((int)blockIdx.x >= nwgG) {
        int e = ((int)blockIdx.x - nwgG) * 256 + threadIdx.x;
        if (e >= 2 * NE) return;
        int br = e >= NE;
        int el = e - br * NE;
        const int* ei = br ? fa.ei_p : fa.ei_t;
        const int* et = br ? fa.et_p : fa.et_t;
        int src = ei[el], dst = ei[NE + el], r = et[el];
        int g = br * NN + dst;
        fa.adj[fa.off[g] + fa.posArr[e]] = src | (r << 28);
        return;
    }

    int nx = C >> 7;                    // 128-col tiles
    int perY = nx * 3 * NBR;
    int orig = blockIdx.x;
    int q = nwgG >> 3, r = nwgG & 7;
    int xcd = orig & 7, pos = orig >> 3;
    int wgid = (xcd < r) ? (xcd * (q + 1) + pos) : (r * (q + 1) + (xcd - r) * q + pos);
    int y = wgid / perY, rem = wgid - y * perY;
    int x = rem / (3 * NBR), zz = rem - x * (3 * NBR);
    int br = zz / 3, z = zz - br * 3;
    GemmJob j = br ? j1 : j0;
    int K = j.K;

    const ushort* B = j.Wt + (size_t)z * C * K;
    int tid = threadIdx.x;
    int lane = tid & 63, wave = tid >> 6;
    int wr = wave >> 1, wc = wave & 1;
    int rowTile = y * 128, colTile = x * 128;

    // per-lane B row bases (4 ni rows, fixed across K)
    const ushort* Brow[4];
#pragma unroll
    for (int ni = 0; ni < 4; ni++)
        Brow[ni] = B + (size_t)(colTile + wc * 64 + ni * 16 + (lane & 15)) * K;

    f32x4 acc[4][4] = {};

    for (int k0 = 0; k0 < K; k0 += 64) {
        __syncthreads();   // prior af reads of smem complete
#pragma unroll
        for (int i = 0; i < 4; i++) {
            int id = i * 256 + tid;
            int rr = id >> 3, ck = id & 7;
            int garow = rowTile + rr;
            if (garow >= M) garow = M - 1;
            GLD_LDS16(j.A + (size_t)garow * K + k0 + ck * 8, &smem[id * 8]);
        }
        __syncthreads();   // A staged
#pragma unroll
        for (int kk = 0; kk < 2; kk++) {
            int kb = kk * 32 + (lane >> 4) * 8;
            bf16x8 af[4], bfr[4];
#pragma unroll
            for (int mi = 0; mi < 4; mi++)
                af[mi] = *(const bf16x8*)&smem[(wr * 64 + mi * 16 + (lane & 15)) * 64 + kb];
#pragma unroll
            for (int ni = 0; ni < 4; ni++)
                bfr[ni] = *(const bf16x8*)&Brow[ni][k0 + kb];   // direct global (L2-resident)
#pragma unroll
            for (int mi = 0; mi < 4; mi++)
#pragma unroll
                for (int ni = 0; ni < 4; ni++)
                    acc[mi][ni] = __builtin_amdgcn_mfma_f32_16x16x32_bf16(af[mi], bfr[ni], acc[mi][ni], 0, 0, 0);
        }
    }

    int lc = lane & 15, lr4 = (lane >> 4) * 4;
    ushort* H = (z == 0) ? j.root : (z == 1 ? j.h0 : j.h1);
    __syncthreads();   // K-loop smem reads complete
    // bounce via [128][128] ushorts = 32 KB, chunk-XOR swizzled
#pragma unroll
    for (int ni = 0; ni < 4; ni++) {
        int col = wc * 64 + ni * 16 + lc;
        float bj = (z == 0) ? j.bias[colTile + col] : 0.f;
#pragma unroll
        for (int mi = 0; mi < 4; mi++)
#pragma unroll
            for (int jj = 0; jj < 4; jj++) {
                int rloc = wr * 64 + mi * 16 + lr4 + jj;
                int chunk = (col >> 3) ^ (rloc & 7);
                smem[rloc * 128 + (chunk << 3) + (col & 7)] = f2bf(acc[mi][ni][jj] + bj);
            }
    }
    __syncthreads();
    // 128 rows x 16 chunks of 16B = 2048 chunks
#pragma unroll
    for (int it = 0; it < 8; it++) {
        int cid = it * 256 + tid;
        int rloc = cid >> 4, cc = cid & 15;
        int grow = rowTile + rloc;
        if (grow < M) {
            int4 v = *(const int4*)&smem[rloc * 128 + ((cc ^ (rloc & 7)) << 3)];
            *(int4*)&H[(size_t)grow * C + colTile + cc * 8] = v;
        }
    }
}

// ---------------- aggregation: v[node] = root[node] + sum_r mean_r(h) ----------------

__global__ __launch_bounds__(256) void k_agg256(const int* __restrict__ off, const int* __restrict__ adj,
                                                const ushort* __restrict__ h0t, const ushort* __restrict__ h1t,
                                                const ushort* __restrict__ roott, ushort* __restrict__ vt,
                                                const ushort* __restrict__ h0p, const ushort* __restrict__ h1p,
                                                const ushort* __restrict__ rootp, ushort* __restrict__ vp,
                                                int perBr) {
    __shared__ float4 shA[2][64];
    __shared__ float4 shB[2][64];
    __shared__ int shc[2][2];
    int br = blockIdx.x >= perBr;
    int bb = blockIdx.x - br * perBr;
    const int* offb = off + br * NN;
    const ushort* h0 = br ? h0p : h0t;
    const ushort* h1 = br ? h1p : h1t;
    const ushort* root = br ? rootp : roott;
    ushort* vout = br ? vp : vt;
    int wave = threadIdx.x >> 6, lane = threadIdx.x & 63;
    int nb = wave >> 1, w = wave & 1;
    int node = bb * 2 + nb;
    int s = offb[node], e = offb[node + 1];
    int len = e - s;
    int mid = s + ((len + 1) >> 1);
    int i0 = w ? mid : s;
    int i1 = w ? e : mid;
    float4 a0 = make_float4(0.f, 0.f, 0.f, 0.f);
    float4 a1 = make_float4(0.f, 0.f, 0.f, 0.f);
    float4 b0 = make_float4(0.f, 0.f, 0.f, 0.f);
    float4 b1 = make_float4(0.f, 0.f, 0.f, 0.f);
    int c0 = 0, c1 = 0;
    int i = i0;
    for (; i + 1 < i1; i += 2) {
        int v0 = adj[i], v1 = adj[i + 1];
        int s0 = v0 & 0x0FFFFFFF, r0 = v0 >> 28;
        int s1 = v1 & 0x0FFFFFFF, r1 = v1 >> 28;
        const ushort* hp0 = r0 ? h1 : h0;
        const ushort* hp1 = r1 ? h1 : h0;
        ushort4 x0 = *(const ushort4*)&hp0[(size_t)s0 * 256 + lane * 4];
        ushort4 x1 = *(const ushort4*)&hp1[(size_t)s1 * 256 + lane * 4];
        if (r0) { a1.x += bf2f(x0.x); a1.y += bf2f(x0.y); a1.z += bf2f(x0.z); a1.w += bf2f(x0.w); c1++; }
        else    { a0.x += bf2f(x0.x); a0.y += bf2f(x0.y); a0.z += bf2f(x0.z); a0.w += bf2f(x0.w); c0++; }
        if (r1) { b1.x += bf2f(x1.x); b1.y += bf2f(x1.y); b1.z += bf2f(x1.z); b1.w += bf2f(x1.w); c1++; }
        else    { b0.x += bf2f(x1.x); b0.y += bf2f(x1.y); b0.z += bf2f(x1.z); b0.w += bf2f(x1.w); c0++; }
    }
    if (i < i1) {
        int v0 = adj[i];
        int s0 = v0 & 0x0FFFFFFF, r0 = v0 >> 28;
        const ushort* hp0 = r0 ? h1 : h0;
        ushort4 x0 = *(const ushort4*)&hp0[(size_t)s0 * 256 + lane * 4];
        if (r0) { a1.x += bf2f(x0.x); a1.y += bf2f(x0.y); a1.z += bf2f(x0.z); a1.w += bf2f(x0.w); c1++; }
        else    { a0.x += bf2f(x0.x); a0.y += bf2f(x0.y); a0.z += bf2f(x0.z); a0.w += bf2f(x0.w); c0++; }
    }
    float4 s0v = make_float4(a0.x + b0.x, a0.y + b0.y, a0.z + b0.z, a0.w + b0.w);
    float4 s1v = make_float4(a1.x + b1.x, a1.y + b1.y, a1.z + b1.z, a1.w + b1.w);
    if (w) {
        shA[nb][lane] = s0v; shB[nb][lane] = s1v;
        if (lane == 0) { shc[nb][0] = c0; shc[nb][1] = c1; }
    }
    __syncthreads();
    if (!w) {
        float4 t0 = shA[nb][lane], t1 = shB[nb][lane];
        c0 += shc[nb][0]; c1 += shc[nb][1];
        float w0 = 1.0f / (float)(c0 > 0 ? c0 : 1);
        float w1 = 1.0f / (float)(c1 > 0 ? c1 : 1);
        ushort4 rt = *(const ushort4*)&root[(size_t)node * 256 + lane * 4];
        ushort4 o;
        o.x = f2bf(bf2f(rt.x) + (s0v.x + t0.x) * w0 + (s1v.x + t1.x) * w1);
        o.y = f2bf(bf2f(rt.y) + (s0v.y + t0.y) * w0 + (s1v.y + t1.y) * w1);
        o.z = f2bf(bf2f(rt.z) + (s0v.z + t0.z) * w0 + (s1v.z + t1.z) * w1);
        o.w = f2bf(bf2f(rt.w) + (s0v.w + t0.w) * w0 + (s1v.w + t1.w) * w1);
        *(ushort4*)&vout[(size_t)node * 256 + lane * 4] = o;
    }
}

__global__ __launch_bounds__(256) void k_agg128(const int* __restrict__ offAll, const int* __restrict__ adj,
                                                const ushort* __restrict__ h0t, const ushort* __restrict__ h1t,
                                                const ushort* __restrict__ roott, ushort* __restrict__ vt,
                                                const ushort* __restrict__ h0p, const ushort* __restrict__ h1p,
                                                const ushort* __restrict__ rootp, ushort* __restrict__ vp) {
    int half = gridDim.x >> 1;
    int br = blockIdx.x >= half;
    int bb = blockIdx.x - br * half;
    int wave = threadIdx.x >> 6, lane = threadIdx.x & 63;
    int node = bb * 4 + wave;
    const int* off = offAll + br * NN;
    const ushort* h0 = br ? h0p : h0t;
    const ushort* h1 = br ? h1p : h1t;
    const ushort* root = br ? rootp : roott;
    ushort* vout = br ? vp : vt;
    int s = off[node], e = off[node + 1];
    int l32 = lane & 31, ep = lane >> 5;
    float4 a0 = make_float4(0.f, 0.f, 0.f, 0.f);
    float4 a1 = make_float4(0.f, 0.f, 0.f, 0.f);
    float4 b0 = make_float4(0.f, 0.f, 0.f, 0.f);
    float4 b1 = make_float4(0.f, 0.f, 0.f, 0.f);
    int c0 = 0, c1 = 0;
    int i = s + ep;
    for (; i + 2 < e; i += 4) {
        int v0 = adj[i], v1 = adj[i + 2];
        int s0 = v0 & 0x0FFFFFFF, r0 = v0 >> 28;
        int s1 = v1 & 0x0FFFFFFF, r1 = v1 >> 28;
        const ushort* hp0 = r0 ? h1 : h0;
        const ushort* hp1 = r1 ? h1 : h0;
        ushort4 x0 = *(const ushort4*)&hp0[(size_t)s0 * 128 + l32 * 4];
        ushort4 x1 = *(const ushort4*)&hp1[(size_t)s1 * 128 + l32 * 4];
        if (r0) { a1.x += bf2f(x0.x); a1.y += bf2f(x0.y); a1.z += bf2f(x0.z); a1.w += bf2f(x0.w); c1++; }
        else    { a0.x += bf2f(x0.x); a0.y += bf2f(x0.y); a0.z += bf2f(x0.z); a0.w += bf2f(x0.w); c0++; }
        if (r1) { b1.x += bf2f(x1.x); b1.y += bf2f(x1.y); b1.z += bf2f(x1.z); b1.w += bf2f(x1.w); c1++; }
        else    { b0.x += bf2f(x1.x); b0.y += bf2f(x1.y); b0.z += bf2f(x1.z); b0.w += bf2f(x1.w); c0++; }
    }
    if (i < e) {
        int v0 = adj[i];
        int s0 = v0 & 0x0FFFFFFF, r0 = v0 >> 28;
        const ushort* hp0 = r0 ? h1 : h0;
        ushort4 x0 = *(const ushort4*)&hp0[(size_t)s0 * 128 + l32 * 4];
        if (r0) { a1.x += bf2f(x0.x); a1.y += bf2f(x0.y); a1.z += bf2f(x0.z); a1.w += bf2f(x0.w); c1++; }
        else    { a0.x += bf2f(x0.x); a0.y += bf2f(x0.y); a0.z += bf2f(x0.z); a0.w += bf2f(x0.w); c0++; }
    }
    float sx0 = a0.x + b0.x, sy0 = a0.y + b0.y, sz0 = a0.z + b0.z, sw0 = a0.w + b0.w;
    float sx1 = a1.x + b1.x, sy1 = a1.y + b1.y, sz1 = a1.z + b1.z, sw1 = a1.w + b1.w;
    sx0 += __shfl_xor(sx0, 32); sy0 += __shfl_xor(sy0, 32);
    sz0 += __shfl_xor(sz0, 32); sw0 += __shfl_xor(sw0, 32);
    sx1 += __shfl_xor(sx1, 32); sy1 += __shfl_xor(sy1, 32);
    sz1 += __shfl_xor(sz1, 32); sw1 += __shfl_xor(sw1, 32);
    c0 += __shfl_xor(c0, 32); c1 += __shfl_xor(c1, 32);
    if (ep == 0) {
        float w0 = 1.0f / (float)(c0 > 0 ? c0 : 1);
        float w1 = 1.0f / (float)(c1 > 0 ? c1 : 1);
        ushort4 rt = *(const ushort4*)&root[(size_t)node * 128 + l32 * 4];
        ushort4 o;
        o.x = f2bf(bf2f(rt.x) + sx0 * w0 + sx1 * w1);
        o.y = f2bf(bf2f(rt.y) + sy0 * w0 + sy1 * w1);
        o.z = f2bf(bf2f(rt.z) + sz0 * w0 + sz1 * w1);
        o.w = f2bf(bf2f(rt.w) + sw0 * w0 + sw1 * w1);
        *(ushort4*)&vout[(size_t)node * 128 + l32 * 4] = o;
    }
}

// ---------------- batchnorm on combined v ----------------

__global__ __launch_bounds__(256) void k_bnstats(const ushort* __restrict__ v0buf, const ushort* __restrict__ v1buf,
                                                 float* __restrict__ part, int C, int M) {
    int br = blockIdx.y;
    const ushort* v = br ? v1buf : v0buf;
    float* P = part + (size_t)br * 2 * C * BNG;
    int tid = threadIdx.x;
    int half = C >> 1;
    int groups = 256 / half;
    int col2 = tid & (half - 1);
    int rg = tid / half;
    float sx = 0.f, sy = 0.f, qx = 0.f, qy = 0.f;
    for (int row = blockIdx.x * groups + rg; row < M; row += BNG * groups) {
        uint rv = *(const uint*)&v[(size_t)row * C + col2 * 2];
        float v0 = bf2f((ushort)(rv & 0xffff));
        float v1 = bf2f((ushort)(rv >> 16));
        sx += v0; qx += v0 * v0;
        sy += v1; qy += v1 * v1;
    }
    __shared__ float4 sh[256];
    sh[tid] = make_float4(sx, sy, qx, qy);
    __syncthreads();
    if (tid < half) {
        float4 a = sh[tid];
        for (int g = 1; g < groups; g++) {
            float4 b = sh[tid + g * half];
            a.x += b.x; a.y += b.y; a.z += b.z; a.w += b.w;
        }
        int c0 = tid * 2;
        P[(size_t)c0 * BNG + blockIdx.x] = a.x;
        P[(size_t)(c0 + 1) * BNG + blockIdx.x] = a.y;
        P[(size_t)(C + c0) * BNG + blockIdx.x] = a.z;
        P[(size_t)(C + c0 + 1) * BNG + blockIdx.x] = a.w;
    }
}

__global__ __launch_bounds__(256) void k_bnreduce(const float* __restrict__ part,
                                                  const float* __restrict__ g0, const float* __restrict__ be0,
                                                  const float* __restrict__ g1, const float* __restrict__ be1,
                                                  float* __restrict__ ss, int C, float invM) {
    int br = blockIdx.y;
    const float* P = part + (size_t)br * 2 * C * BNG;
    const float* g = br ? g1 : g0;
    const float* be = br ? be1 : be0;
    float* S = ss + br * 2 * C;
    int wv = threadIdx.x >> 6, lane = threadIdx.x & 63;
    int c = blockIdx.x * 4 + wv;
    if (c >= C) return;
    float s = P[(size_t)c * BNG + lane] + P[(size_t)c * BNG + 64 + lane];
    float s2 = P[(size_t)(C + c) * BNG + lane] + P[(size_t)(C + c) * BNG + 64 + lane];
#pragma unroll
    for (int o = 32; o >= 1; o >>= 1) {
        s += __shfl_xor(s, o, 64);
        s2 += __shfl_xor(s2, o, 64);
    }
    if (lane == 0) {
        float mu = s * invM;
        float var = s2 * invM - mu * mu;
        float sc = g[c] * rsqrtf(var + 1e-5f);
        S[c] = sc;
        S[C + c] = be[c] - mu * sc;
    }
}

__global__ __launch_bounds__(256) void k_bnapply(const ushort* __restrict__ v0buf, const ushort* __restrict__ v1buf,
                                                 const float* __restrict__ ss, int C, int M,
                                                 ushort* __restrict__ ob0, ushort* __restrict__ ob1) {
    int br = blockIdx.y;
    const ushort* v = br ? v1buf : v0buf;
    const float* S = ss + br * 2 * C;
    int i = blockIdx.x * 256 + threadIdx.x;
    int total4 = M * C / 4;
    if (i >= total4) return;
    ushort4 vv = *(const ushort4*)&v[(size_t)i * 4];
    int c0 = (i * 4) & (C - 1);
    float y0 = bf2f(vv.x) * S[c0 + 0] + S[C + c0 + 0];
    float y1 = bf2f(vv.y) * S[c0 + 1] + S[C + c0 + 1];
    float y2 = bf2f(vv.z) * S[c0 + 2] + S[C + c0 + 2];
    float y3 = bf2f(vv.w) * S[c0 + 3] + S[C + c0 + 3];
    y0 = y0 >= 0.f ? y0 : 0.01f * y0;
    y1 = y1 >= 0.f ? y1 : 0.01f * y1;
    y2 = y2 >= 0.f ? y2 : 0.01f * y2;
    y3 = y3 >= 0.f ? y3 : 0.01f * y3;
    ushort* ob = br ? ob1 : ob0;
    ushort4 o;
    o.x = f2bf(y0); o.y = f2bf(y1); o.z = f2bf(y2); o.w = f2bf(y3);
    *(ushort4*)&ob[(size_t)i * 4] = o;
}

// ---------------- pooling with fused layer-2 BN+leaky ----------------

__global__ __launch_bounds__(512) void k_pool2(const ushort* __restrict__ v2t, const ushort* __restrict__ v2p,
                                               const int* __restrict__ bt, const int* __restrict__ bp,
                                               const float* __restrict__ ss, float* __restrict__ out) {
    int blk = blockIdx.x;
    int br = blk >> 6, b = blk & 63;
    const ushort* v = br ? v2p : v2t;
    const int* bat = br ? bp : bt;
    const float* S = ss + br * 2 * 128;
    __shared__ int se[2];
    if (threadIdx.x < 2) {
        int val = b + (int)threadIdx.x;
        int lo = 0, hi = NN;
        while (lo < hi) {
            int mid = (lo + hi) >> 1;
            if (bat[mid] < val) lo = mid + 1; else hi = mid;
        }
        se[threadIdx.x] = lo;
    }
    __syncthreads();
    int s = se[0], e = se[1];
    int t2 = threadIdx.x & 63, rg = threadIdx.x >> 6;
    float sc0 = S[t2 * 2], sh0 = S[128 + t2 * 2];
    float sc1 = S[t2 * 2 + 1], sh1 = S[128 + t2 * 2 + 1];
    float ax = 0.f, ay = 0.f;
    for (int r = s + rg; r < e; r += 8) {
        uint rv = *(const uint*)&v[(size_t)r * 128 + t2 * 2];
        float v0 = bf2f((ushort)(rv & 0xffff)) * sc0 + sh0;
        float v1 = bf2f((ushort)(rv >> 16)) * sc1 + sh1;
        v0 = v0 >= 0.f ? v0 : 0.01f * v0;
        v1 = v1 >= 0.f ? v1 : 0.01f * v1;
        ax += v0; ay += v1;
    }
    __shared__ float2 sh[512];
    sh[threadIdx.x] = make_float2(ax, ay);
    __syncthreads();
    if (rg == 0) {
        float2 a = sh[t2];
#pragma unroll
        for (int g = 1; g < 8; g++) {
            float2 vv = sh[t2 + g * 64];
            a.x += vv.x; a.y += vv.y;
        }
        int cnt = e - s;
        float inv = 1.0f / (float)(cnt > 0 ? cnt : 1);
        out[(br * 64 + b) * 128 + t2 * 2] = a.x * inv;
        out[(br * 64 + b) * 128 + t2 * 2 + 1] = a.y * inv;
    }
}

// ---------------- host orchestration ----------------

extern "C" void kernel_launch(void* const* d_in, const int* in_sizes, int n_in,
                              void* d_out, int out_size, void* d_ws, size_t ws_size,
                              hipStream_t stream) {
    const float* x_t = (const float*)d_in[0];
    const float* x_p = (const float*)d_in[1];
    const int* ei_t = (const int*)d_in[2];
    const int* et_t = (const int*)d_in[3];
    const int* bat_t = (const int*)d_in[4];
    const int* ei_p = (const int*)d_in[5];
    const int* et_p = (const int*)d_in[6];
    const int* bat_p = (const int*)d_in[7];
    const float* w_t1_rel = (const float*)d_in[8];
    const float* w_t1_root = (const float*)d_in[9];
    const float* b_t1 = (const float*)d_in[10];
    const float* w_t2_rel = (const float*)d_in[11];
    const float* w_t2_root = (const float*)d_in[12];
    const float* b_t2 = (const float*)d_in[13];
    const float* w_p1_rel = (const float*)d_in[14];
    const float* w_p1_root = (const float*)d_in[15];
    const float* b_p1 = (const float*)d_in[16];
    const float* w_p2_rel = (const float*)d_in[17];
    const float* w_p2_root = (const float*)d_in[18];
    const float* b_p2 = (const float*)d_in[19];
    const float* g_t1 = (const float*)d_in[20]; const float* be_t1 = (const float*)d_in[21];
    const float* g_t2 = (const float*)d_in[22]; const float* be_t2 = (const float*)d_in[23];
    const float* g_p1 = (const float*)d_in[24]; const float* be_p1 = (const float*)d_in[25];
    const float* g_p2 = (const float*)d_in[26]; const float* be_p2 = (const float*)d_in[27];

    char* wp = (char*)d_ws;
    auto alloc = [&](size_t b) -> void* {
        void* p = (void*)wp;
        wp += (b + 255) & ~(size_t)255;
        return p;
    };

    const bool MERGED = ws_size >= (size_t)137 * 1000 * 1000;

    dim3 blk(256);
    const int EB2 = (2 * NE) / 256;          // 2500
    const int SCB2 = (2 * NN + 255) / 256;
    const int nMT = (NN + 127) / 128;

    ushort* xt_bf; ushort* xp_bf;
    ushort *h0t1, *h1t1, *h0p1, *h1p1;
    ushort *root1t, *v1t, *root1p, *v1p;
    ushort *a1t, *a1p;
    ushort *root2t, *v2t, *root2p, *v2p;
    ushort *h0t2, *h1t2, *h0p2, *h1p2;
    ushort* wtb; int* adj; int* posArr; int* off; int* deg; int* csum;
    float* part; float* ss;

    if (MERGED) {
        xt_bf = (ushort*)alloc((size_t)NN * 768 * 2);
        xp_bf = (ushort*)alloc((size_t)NN * 128 * 2);
        h0t1 = (ushort*)alloc((size_t)NN * 256 * 2);
        h1t1 = (ushort*)alloc((size_t)NN * 256 * 2);
        h0p1 = (ushort*)alloc((size_t)NN * 256 * 2);
        h1p1 = (ushort*)alloc((size_t)NN * 256 * 2);
        root1t = (ushort*)alloc((size_t)NN * 256 * 2);
        v1t = (ushort*)alloc((size_t)NN * 256 * 2);
        root1p = (ushort*)alloc((size_t)NN * 256 * 2);
        v1p = (ushort*)alloc((size_t)NN * 256 * 2);
        a1t = (ushort*)alloc((size_t)NN * 256 * 2);
        wtb = (ushort*)alloc((size_t)(3 * 768 * 256 + 3 * 128 * 256 + 2 * 3 * 256 * 128) * 2);
        adj = (int*)alloc((size_t)2 * NE * 4);
        posArr = (int*)alloc((size_t)2 * NE * 4);
        off = (int*)alloc((size_t)(2 * NN + 1) * 4);
        deg = (int*)alloc((size_t)2 * NN * 4);
        csum = (int*)alloc(256 * 4);
        part = (float*)alloc((size_t)2 * 2 * 256 * BNG * 4);
        ss = (float*)alloc(1024 * 4);
        root2t = xt_bf;
        v2t = root2t + (size_t)NN * 128;
        root2p = v2t + (size_t)NN * 128;
        v2p = root2p + (size_t)NN * 128;
        a1p = v2p + (size_t)NN * 128;
        h0t2 = h0t1;                       h0p2 = h0t1 + (size_t)NN * 128;
        h1t2 = h1t1;                       h1p2 = h1t1 + (size_t)NN * 128;
    } else {
        xt_bf = (ushort*)alloc((size_t)NN * 768 * 2);
        xp_bf = (ushort*)alloc((size_t)NN * 128 * 2);
        ushort* h0b = (ushort*)alloc((size_t)NN * 256 * 2);
        ushort* h1b = (ushort*)alloc((size_t)NN * 256 * 2);
        ushort* root1 = (ushort*)alloc((size_t)NN * 256 * 2);
        ushort* v1 = (ushort*)alloc((size_t)NN * 256 * 2);
        a1t = (ushort*)alloc((size_t)NN * 256 * 2);
        wtb = (ushort*)alloc((size_t)(3 * 768 * 256 + 3 * 128 * 256 + 2 * 3 * 256 * 128) * 2);
        adj = (int*)alloc((size_t)2 * NE * 4);
        posArr = (int*)alloc((size_t)2 * NE * 4);
        off = (int*)alloc((size_t)(2 * NN + 1) * 4);
        deg = (int*)alloc((size_t)2 * NN * 4);
        csum = (int*)alloc(256 * 4);
        part = (float*)alloc((size_t)2 * 2 * 256 * BNG * 4);
        ss = (float*)alloc(1024 * 4);
        h0t1 = h0b; h1t1 = h1b; h0p1 = h0b; h1p1 = h1b;
        root1t = root1; v1t = v1; root1p = root1; v1p = v1;
        root2t = xt_bf;
        v2t = root2t + (size_t)NN * 128;
        root2p = v2t + (size_t)NN * 128;
        v2p = root2p + (size_t)NN * 128;
        a1p = v2p + (size_t)NN * 128;
        h0t2 = h0b;                        h0p2 = h0b + (size_t)NN * 128;
        h1t2 = h1b;                        h1p2 = h1b + (size_t)NN * 128;
    }

    ushort* wt_t1 = wtb;
    ushort* wt_p1 = wt_t1 + 3 * 768 * 256;
    ushort* wt_t2 = wt_p1 + 3 * 128 * 256;
    ushort* wt_p2 = wt_t2 + 3 * 256 * 128;
    WtJob j0 = {w_t1_root, w_t1_rel, wt_t1, 768, 256};
    WtJob j1 = {w_p1_root, w_p1_rel, wt_p1, 128, 256};
    WtJob j2 = {w_t2_root, w_t2_rel, wt_t2, 256, 128};
    WtJob j3 = {w_p2_root, w_p2_rel, wt_p2, 256, 128};

    int n4t = NN * 768 / 4, n4p = NN * 128 / 4;
    int nbCast = (n4t + n4p + 255) / 256;

    // ---- fused prep: countpos ∥ cast_x ∥ cast_wt ----
    hipMemsetAsync(deg, 0, (size_t)2 * NN * 4, stream);
    k_prep<<<EB2 + nbCast + 864, blk, 0, stream>>>(ei_t, ei_p, deg, posArr,
                                                   x_t, x_p, xt_bf, xp_bf, n4t, n4p,
                                                   j0, j1, j2, j3, 576, 672, 768, EB2, nbCast);
    k_scan_local<<<SCB2, blk, 0, stream>>>(deg, off, csum, 2 * NN);
    k_scan_csum<<<1, 256, 0, stream>>>(csum, off + 2 * NN, SCB2);
    k_scan_add<<<SCB2, blk, 0, stream>>>(off, csum, 2 * NN);

    FillArgs fa = {ei_t, et_t, ei_p, et_p, off, posArr, adj};
    GemmJob Gt1 = {xt_bf, wt_t1, b_t1, root1t, h0t1, h1t1, 768};
    GemmJob Gp1 = {xp_bf, wt_p1, b_p1, root1p, h0p1, h1p1, 128};

    if (MERGED) {
        int nwgG = nMT * 2 * 3 * 2;  // 1884
        k_gemm_fill<<<nwgG + EB2, blk, 0, stream>>>(Gt1, Gp1, NN, 256, 2, nwgG, fa);
        k_agg256<<<NN, blk, 0, stream>>>(off, adj, h0t1, h1t1, root1t, v1t,
                                         h0p1, h1p1, root1p, v1p, NN / 2);
        k_bnstats<<<dim3(BNG, 2), blk, 0, stream>>>(v1t, v1p, part, 256, NN);
        k_bnreduce<<<dim3(64, 2), blk, 0, stream>>>(part, g_t1, be_t1, g_p1, be_p1, ss, 256, 1.0f / NN);
        k_bnapply<<<dim3((NN * 256 / 4 + 255) / 256, 2), blk, 0, stream>>>(
            v1t, v1p, ss, 256, NN, a1t, a1p);
    } else {
        int nwgG = nMT * 2 * 3;
        k_gemm_fill<<<nwgG + EB2, blk, 0, stream>>>(Gt1, Gt1, NN, 256, 1, nwgG, fa);
        k_agg256<<<NN / 2, blk, 0, stream>>>(off, adj, h0t1, h1t1, root1t, v1t,
                                             h0t1, h1t1, root1t, v1t, NN / 2);
        k_bnstats<<<dim3(BNG, 1), blk, 0, stream>>>(v1t, v1t, part, 256, NN);
        k_bnreduce<<<dim3(64, 1), blk, 0, stream>>>(part, g_t1, be_t1, g_t1, be_t1, ss, 256, 1.0f / NN);
        k_bnapply<<<dim3((NN * 256 / 4 + 255) / 256, 1), blk, 0, stream>>>(
            v1t, v1t, ss, 256, NN, a1t, a1t);

        k_gemm_fill<<<nwgG, blk, 0, stream>>>(Gp1, Gp1, NN, 256, 1, nwgG, fa);
        k_agg256<<<NN / 2, blk, 0, stream>>>(off + NN, adj, h0p1, h1p1, root1p, v1p,
                                             h0p1, h1p1, root1p, v1p, NN / 2);
        k_bnstats<<<dim3(BNG, 1), blk, 0, stream>>>(v1p, v1p, part, 256, NN);
        k_bnreduce<<<dim3(64, 1), blk, 0, stream>>>(part, g_p1, be_p1, g_p1, be_p1, ss, 256, 1.0f / NN);
        k_bnapply<<<dim3((NN * 256 / 4 + 255) / 256, 1), blk, 0, stream>>>(
            v1p, v1p, ss, 256, NN, a1p, a1p);
    }

    // ---- layer 2, both branches merged ----
    GemmJob Gt2 = {a1t, wt_t2, b_t2, root2t, h0t2, h1t2, 256};
    GemmJob Gp2 = {a1p, wt_p2, b_p2, root2p, h0p2, h1p2, 256};
    int nwg2 = nMT * 1 * 3 * 2;  // 942
    k_gemm_fill<<<nwg2, blk, 0, stream>>>(Gt2, Gp2, NN, 128, 2, nwg2, fa);
    k_agg128<<<2 * (NN / 4), blk, 0, stream>>>(off, adj, h0t2, h1t2, root2t, v2t,
                                               h0p2, h1p2, root2p, v2p);
    k_bnstats<<<dim3(BNG, 2), blk, 0, stream>>>(v2t, v2p, part, 128, NN);
    k_bnreduce<<<dim3(32, 2), blk, 0, stream>>>(part, g_t2, be_t2, g_p2, be_p2, ss, 128, 1.0f / NN);

    // ---- pool both ----
    k_pool2<<<128, 512, 0, stream>>>(v2t, v2p, bat_t, bat_p, ss, (float*)d_out);
}

// Round 16
// 280.865 us; speedup vs baseline: 1.1645x; 1.1645x over previous
//
#include <hip/hip_runtime.h>

#define NN 20000
#define NE 320000
#define NB 64
#define BNG 128  // bnstats partial-sum blocks

typedef __attribute__((ext_vector_type(4))) float f32x4;
typedef __attribute__((ext_vector_type(8))) __bf16 bf16x8;

static __device__ __forceinline__ ushort f2bf(float f) {
    uint u = __builtin_bit_cast(uint, f);
    uint r = (u + 0x7fffu + ((u >> 16) & 1u)) >> 16;
    return (ushort)r;
}
static __device__ __forceinline__ float bf2f(ushort u) {
    return __builtin_bit_cast(float, (uint)u << 16);
}

#define GLD_LDS16(g, l)                                                                     \
    __builtin_amdgcn_global_load_lds((__attribute__((address_space(1))) void*)(g),          \
                                     (__attribute__((address_space(3))) void*)(l), 16, 0, 0)

struct WtJob { const float* root; const float* rel; ushort* dst; int K; int C; };
struct FillArgs { const int* ei_t; const int* et_t; const int* ei_p; const int* et_p;
                  const int* off; const int* posArr; int* adj; };

// ---------------- fused prep: countpos ∥ cast_x ∥ cast_wt ----------

__global__ __launch_bounds__(256) void k_prep(const int* __restrict__ ei_t, const int* __restrict__ ei_p,
                                              int* __restrict__ deg, int* __restrict__ posArr,
                                              const float* __restrict__ xt, const float* __restrict__ xp,
                                              ushort* __restrict__ ot, ushort* __restrict__ op,
                                              int n4t, int n4p,
                                              WtJob j0, WtJob j1, WtJob j2, WtJob j3,
                                              int c1, int c2, int c3, int nbCount, int nbCast) {
    __shared__ float tile[32][33];
    int bid = blockIdx.x;
    int tid = threadIdx.x;
    if (bid < nbCount) {
        int e = bid * 256 + tid;
        if (e >= 2 * NE) return;
        int br = e >= NE;
        int el = e - br * NE;
        const int* ei = br ? ei_p : ei_t;
        int dst = ei[NE + el];
        posArr[e] = atomicAdd(&deg[br * NN + dst], 1);
        return;
    }
    if (bid < nbCount + nbCast) {
        int i = (bid - nbCount) * 256 + tid;
        const float* in; ushort* out; int j;
        if (i < n4t) { in = xt; out = ot; j = i; }
        else { j = i - n4t; if (j >= n4p) return; in = xp; out = op; }
        float4 v = *(const float4*)&in[(size_t)j * 4];
        ushort4 o;
        o.x = f2bf(v.x); o.y = f2bf(v.y); o.z = f2bf(v.z); o.w = f2bf(v.w);
        *(ushort4*)&out[(size_t)j * 4] = o;
        return;
    }
    int lt0 = bid - nbCount - nbCast;
    WtJob j; int lt;
    if (lt0 < c1) { j = j0; lt = lt0; }
    else if (lt0 < c2) { j = j1; lt = lt0 - c1; }
    else if (lt0 < c3) { j = j2; lt = lt0 - c2; }
    else { j = j3; lt = lt0 - c3; }
    int nx = j.K >> 5, ny = j.C >> 5;
    int mat = lt / (nx * ny);
    int r2 = lt - mat * (nx * ny);
    int kx = r2 % nx, cy = r2 / nx;
    int KC = j.K * j.C;
    const float* W = (mat == 0) ? j.root : j.rel + (size_t)(mat - 1) * KC;
    int k0 = kx * 32, c0 = cy * 32;
    int tx = tid & 31, ty = tid >> 5;
#pragma unroll
    for (int i = 0; i < 4; i++)
        tile[ty + i * 8][tx] = W[(size_t)(k0 + ty + i * 8) * j.C + c0 + tx];
    __syncthreads();
#pragma unroll
    for (int i = 0; i < 4; i++)
        j.dst[(size_t)mat * KC + (size_t)(c0 + ty + i * 8) * j.K + k0 + tx] = f2bf(tile[tx][ty + i * 8]);
}

// ---------------- scans ----------------

__global__ __launch_bounds__(256) void k_scan_local(const int* __restrict__ deg, int* __restrict__ off,
                                                    int* __restrict__ csum, int n) {
    __shared__ int sh[256];
    int base = blockIdx.x * 256, tid = threadIdx.x;
    int v = (base + tid < n) ? deg[base + tid] : 0;
    sh[tid] = v; __syncthreads();
    for (int o = 1; o < 256; o <<= 1) {
        int t = (tid >= o) ? sh[tid - o] : 0;
        __syncthreads();
        sh[tid] += t;
        __syncthreads();
    }
    if (base + tid < n) off[base + tid] = sh[tid] - v;  // exclusive
    if (tid == 255) csum[blockIdx.x] = sh[255];
}

__global__ void k_scan_csum(int* __restrict__ csum, int* __restrict__ offN, int nc) {
    __shared__ int sh[256];
    int tid = threadIdx.x;
    int v = (tid < nc) ? csum[tid] : 0;
    sh[tid] = v; __syncthreads();
    for (int o = 1; o < 256; o <<= 1) {
        int t = (tid >= o) ? sh[tid - o] : 0;
        __syncthreads();
        sh[tid] += t;
        __syncthreads();
    }
    if (tid < nc) csum[tid] = sh[tid] - v;  // exclusive
    if (tid == 255) offN[0] = sh[255];
}

__global__ __launch_bounds__(256) void k_scan_add(int* __restrict__ off, const int* __restrict__ csum, int n) {
    int i = blockIdx.x * 256 + threadIdx.x;
    if (i < n) off[i] += csum[blockIdx.x];
}

// ---------------- MFMA GEMM (z-merged, bf16 outs) ∥ fillpos ----------

struct GemmJob { const ushort* A; const ushort* Wt; const float* bias;
                 ushort* root; ushort* h0; ushort* h1; int K; };

__global__ __launch_bounds__(256, 3) void k_gemm_fill(GemmJob j0, GemmJob j1, int M, int C, int NBR,
                                                      int nwgG, FillArgs fa) {
    __shared__ ushort smem[20480];  // As[128*64] | Bs0 Bs1 Bs2 [64*64 each] = 40 KB

    if ((int)blockIdx.x >= nwgG) {
        int e = ((int)blockIdx.x - nwgG) * 256 + threadIdx.x;
        if (e >= 2 * NE) return;
        int br = e >= NE;
        int el = e - br * NE;
        const int* ei = br ? fa.ei_p : fa.ei_t;
        const int* et = br ? fa.et_p : fa.et_t;
        int src = ei[el], dst = ei[NE + el], r = et[el];
        int g = br * NN + dst;
        fa.adj[fa.off[g] + fa.posArr[e]] = src | (r << 28);
        return;
    }

    int nx = C >> 6;
    int perY = nx * NBR;
    int orig = blockIdx.x;
    int q = nwgG >> 3, r = nwgG & 7;
    int xcd = orig & 7, pos = orig >> 3;
    int wgid = (xcd < r) ? (xcd * (q + 1) + pos) : (r * (q + 1) + (xcd - r) * q + pos);
    int y = wgid / perY, rem = wgid - y * perY;
    int br = rem / nx, x = rem - br * nx;
    GemmJob j = br ? j1 : j0;
    int K = j.K;

    int tid = threadIdx.x;
    int lane = tid & 63, wave = tid >> 6;
    int wr = wave >> 1, wc = wave & 1;
    int rowTile = y * 128, colTile = x * 64;

    f32x4 acc[3][4][2] = {};

    for (int k0 = 0; k0 < K; k0 += 64) {
        __syncthreads();
#pragma unroll
        for (int i = 0; i < 4; i++) {
            int id = i * 256 + tid;
            int rr = id >> 3, ck = id & 7;
            int garow = rowTile + rr;
            if (garow >= M) garow = M - 1;
            GLD_LDS16(j.A + (size_t)garow * K + k0 + ck * 8, &smem[id * 8]);
        }
#pragma unroll
        for (int z = 0; z < 3; z++) {
            const ushort* Bz = j.Wt + (size_t)z * C * K;
#pragma unroll
            for (int i = 0; i < 2; i++) {
                int id = i * 256 + tid;
                int rr = id >> 3, ck = id & 7;
                GLD_LDS16(Bz + (size_t)(colTile + rr) * K + k0 + ck * 8,
                          &smem[8192 + z * 4096 + id * 8]);
            }
        }
        __syncthreads();
#pragma unroll
        for (int kk = 0; kk < 2; kk++) {
            int kb = kk * 32 + (lane >> 4) * 8;
            bf16x8 af[4];
#pragma unroll
            for (int mi = 0; mi < 4; mi++)
                af[mi] = *(const bf16x8*)&smem[(wr * 64 + mi * 16 + (lane & 15)) * 64 + kb];
#pragma unroll
            for (int z = 0; z < 3; z++) {
                bf16x8 bfr[2];
#pragma unroll
                for (int ni = 0; ni < 2; ni++)
                    bfr[ni] = *(const bf16x8*)&smem[8192 + z * 4096 +
                                                    (wc * 32 + ni * 16 + (lane & 15)) * 64 + kb];
#pragma unroll
                for (int mi = 0; mi < 4; mi++)
#pragma unroll
                    for (int ni = 0; ni < 2; ni++)
                        acc[z][mi][ni] =
                            __builtin_amdgcn_mfma_f32_16x16x32_bf16(af[mi], bfr[ni], acc[z][mi][ni], 0, 0, 0);
            }
        }
    }

    int lc = lane & 15, lr4 = (lane >> 4) * 4;
#pragma unroll
    for (int z = 0; z < 3; z++) {
        ushort* H = (z == 0) ? j.root : (z == 1 ? j.h0 : j.h1);
        __syncthreads();
#pragma unroll
        for (int ni = 0; ni < 2; ni++) {
            int cl = wc * 32 + ni * 16 + lc;
            float bj = (z == 0) ? j.bias[colTile + cl] : 0.f;
#pragma unroll
            for (int mi = 0; mi < 4; mi++)
#pragma unroll
                for (int jj = 0; jj < 4; jj++) {
                    int rloc = wr * 64 + mi * 16 + lr4 + jj;
                    int chunk = (cl >> 3) ^ (rloc & 7);
                    smem[rloc * 64 + (chunk << 3) + (cl & 7)] = f2bf(acc[z][mi][ni][jj] + bj);
                }
        }
        __syncthreads();
#pragma unroll
        for (int it = 0; it < 4; it++) {
            int cid = it * 256 + tid;
            int rloc = cid >> 3, cc = cid & 7;
            int grow = rowTile + rloc;
            if (grow < M) {
                int4 v = *(const int4*)&smem[rloc * 64 + ((cc ^ (rloc & 7)) << 3)];
                *(int4*)&H[(size_t)grow * C + colTile + cc * 8] = v;
            }
        }
    }
}

// ---------------- aggregation: v[node] = root[node] + sum_r mean_r(h) ----------------

__global__ __launch_bounds__(256) void k_agg256(const int* __restrict__ off, const int* __restrict__ adj,
                                                const ushort* __restrict__ h0t, const ushort* __restrict__ h1t,
                                                const ushort* __restrict__ roott, ushort* __restrict__ vt,
                                                const ushort* __restrict__ h0p, const ushort* __restrict__ h1p,
                                                const ushort* __restrict__ rootp, ushort* __restrict__ vp,
                                                int perBr) {
    __shared__ float4 shA[2][64];
    __shared__ float4 shB[2][64];
    __shared__ int shc[2][2];
    int br = blockIdx.x >= perBr;
    int bb = blockIdx.x - br * perBr;
    const int* offb = off + br * NN;
    const ushort* h0 = br ? h0p : h0t;
    const ushort* h1 = br ? h1p : h1t;
    const ushort* root = br ? rootp : roott;
    ushort* vout = br ? vp : vt;
    int wave = threadIdx.x >> 6, lane = threadIdx.x & 63;
    int nb = wave >> 1, w = wave & 1;
    int node = bb * 2 + nb;
    int s = offb[node], e = offb[node + 1];
    int len = e - s;
    int mid = s + ((len + 1) >> 1);
    int i0 = w ? mid : s;
    int i1 = w ? e : mid;
    float4 a0 = make_float4(0.f, 0.f, 0.f, 0.f);
    float4 a1 = make_float4(0.f, 0.f, 0.f, 0.f);
    float4 b0 = make_float4(0.f, 0.f, 0.f, 0.f);
    float4 b1 = make_float4(0.f, 0.f, 0.f, 0.f);
    int c0 = 0, c1 = 0;
    int i = i0;
    for (; i + 1 < i1; i += 2) {
        int v0 = adj[i], v1 = adj[i + 1];
        int s0 = v0 & 0x0FFFFFFF, r0 = v0 >> 28;
        int s1 = v1 & 0x0FFFFFFF, r1 = v1 >> 28;
        const ushort* hp0 = r0 ? h1 : h0;
        const ushort* hp1 = r1 ? h1 : h0;
        ushort4 x0 = *(const ushort4*)&hp0[(size_t)s0 * 256 + lane * 4];
        ushort4 x1 = *(const ushort4*)&hp1[(size_t)s1 * 256 + lane * 4];
        if (r0) { a1.x += bf2f(x0.x); a1.y += bf2f(x0.y); a1.z += bf2f(x0.z); a1.w += bf2f(x0.w); c1++; }
        else    { a0.x += bf2f(x0.x); a0.y += bf2f(x0.y); a0.z += bf2f(x0.z); a0.w += bf2f(x0.w); c0++; }
        if (r1) { b1.x += bf2f(x1.x); b1.y += bf2f(x1.y); b1.z += bf2f(x1.z); b1.w += bf2f(x1.w); c1++; }
        else    { b0.x += bf2f(x1.x); b0.y += bf2f(x1.y); b0.z += bf2f(x1.z); b0.w += bf2f(x1.w); c0++; }
    }
    if (i < i1) {
        int v0 = adj[i];
        int s0 = v0 & 0x0FFFFFFF, r0 = v0 >> 28;
        const ushort* hp0 = r0 ? h1 : h0;
        ushort4 x0 = *(const ushort4*)&hp0[(size_t)s0 * 256 + lane * 4];
        if (r0) { a1.x += bf2f(x0.x); a1.y += bf2f(x0.y); a1.z += bf2f(x0.z); a1.w += bf2f(x0.w); c1++; }
        else    { a0.x += bf2f(x0.x); a0.y += bf2f(x0.y); a0.z += bf2f(x0.z); a0.w += bf2f(x0.w); c0++; }
    }
    float4 s0v = make_float4(a0.x + b0.x, a0.y + b0.y, a0.z + b0.z, a0.w + b0.w);
    float4 s1v = make_float4(a1.x + b1.x, a1.y + b1.y, a1.z + b1.z, a1.w + b1.w);
    if (w) {
        shA[nb][lane] = s0v; shB[nb][lane] = s1v;
        if (lane == 0) { shc[nb][0] = c0; shc[nb][1] = c1; }
    }
    __syncthreads();
    if (!w) {
        float4 t0 = shA[nb][lane], t1 = shB[nb][lane];
        c0 += shc[nb][0]; c1 += shc[nb][1];
        float w0 = 1.0f / (float)(c0 > 0 ? c0 : 1);
        float w1 = 1.0f / (float)(c1 > 0 ? c1 : 1);
        ushort4 rt = *(const ushort4*)&root[(size_t)node * 256 + lane * 4];
        ushort4 o;
        o.x = f2bf(bf2f(rt.x) + (s0v.x + t0.x) * w0 + (s1v.x + t1.x) * w1);
        o.y = f2bf(bf2f(rt.y) + (s0v.y + t0.y) * w0 + (s1v.y + t1.y) * w1);
        o.z = f2bf(bf2f(rt.z) + (s0v.z + t0.z) * w0 + (s1v.z + t1.z) * w1);
        o.w = f2bf(bf2f(rt.w) + (s0v.w + t0.w) * w0 + (s1v.w + t1.w) * w1);
        *(ushort4*)&vout[(size_t)node * 256 + lane * 4] = o;
    }
}

__global__ __launch_bounds__(256) void k_agg128(const int* __restrict__ offAll, const int* __restrict__ adj,
                                                const ushort* __restrict__ h0t, const ushort* __restrict__ h1t,
                                                const ushort* __restrict__ roott, ushort* __restrict__ vt,
                                                const ushort* __restrict__ h0p, const ushort* __restrict__ h1p,
                                                const ushort* __restrict__ rootp, ushort* __restrict__ vp) {
    int half = gridDim.x >> 1;
    int br = blockIdx.x >= half;
    int bb = blockIdx.x - br * half;
    int wave = threadIdx.x >> 6, lane = threadIdx.x & 63;
    int node = bb * 4 + wave;
    const int* off = offAll + br * NN;
    const ushort* h0 = br ? h0p : h0t;
    const ushort* h1 = br ? h1p : h1t;
    const ushort* root = br ? rootp : roott;
    ushort* vout = br ? vp : vt;
    int s = off[node], e = off[node + 1];
    int l32 = lane & 31, ep = lane >> 5;
    float4 a0 = make_float4(0.f, 0.f, 0.f, 0.f);
    float4 a1 = make_float4(0.f, 0.f, 0.f, 0.f);
    float4 b0 = make_float4(0.f, 0.f, 0.f, 0.f);
    float4 b1 = make_float4(0.f, 0.f, 0.f, 0.f);
    int c0 = 0, c1 = 0;
    int i = s + ep;
    for (; i + 2 < e; i += 4) {
        int v0 = adj[i], v1 = adj[i + 2];
        int s0 = v0 & 0x0FFFFFFF, r0 = v0 >> 28;
        int s1 = v1 & 0x0FFFFFFF, r1 = v1 >> 28;
        const ushort* hp0 = r0 ? h1 : h0;
        const ushort* hp1 = r1 ? h1 : h0;
        ushort4 x0 = *(const ushort4*)&hp0[(size_t)s0 * 128 + l32 * 4];
        ushort4 x1 = *(const ushort4*)&hp1[(size_t)s1 * 128 + l32 * 4];
        if (r0) { a1.x += bf2f(x0.x); a1.y += bf2f(x0.y); a1.z += bf2f(x0.z); a1.w += bf2f(x0.w); c1++; }
        else    { a0.x += bf2f(x0.x); a0.y += bf2f(x0.y); a0.z += bf2f(x0.z); a0.w += bf2f(x0.w); c0++; }
        if (r1) { b1.x += bf2f(x1.x); b1.y += bf2f(x1.y); b1.z += bf2f(x1.z); b1.w += bf2f(x1.w); c1++; }
        else    { b0.x += bf2f(x1.x); b0.y += bf2f(x1.y); b0.z += bf2f(x1.z); b0.w += bf2f(x1.w); c0++; }
    }
    if (i < e) {
        int v0 = adj[i];
        int s0 = v0 & 0x0FFFFFFF, r0 = v0 >> 28;
        const ushort* hp0 = r0 ? h1 : h0;
        ushort4 x0 = *(const ushort4*)&hp0[(size_t)s0 * 128 + l32 * 4];
        if (r0) { a1.x += bf2f(x0.x); a1.y += bf2f(x0.y); a1.z += bf2f(x0.z); a1.w += bf2f(x0.w); c1++; }
        else    { a0.x += bf2f(x0.x); a0.y += bf2f(x0.y); a0.z += bf2f(x0.z); a0.w += bf2f(x0.w); c0++; }
    }
    float sx0 = a0.x + b0.x, sy0 = a0.y + b0.y, sz0 = a0.z + b0.z, sw0 = a0.w + b0.w;
    float sx1 = a1.x + b1.x, sy1 = a1.y + b1.y, sz1 = a1.z + b1.z, sw1 = a1.w + b1.w;
    sx0 += __shfl_xor(sx0, 32); sy0 += __shfl_xor(sy0, 32);
    sz0 += __shfl_xor(sz0, 32); sw0 += __shfl_xor(sw0, 32);
    sx1 += __shfl_xor(sx1, 32); sy1 += __shfl_xor(sy1, 32);
    sz1 += __shfl_xor(sz1, 32); sw1 += __shfl_xor(sw1, 32);
    c0 += __shfl_xor(c0, 32); c1 += __shfl_xor(c1, 32);
    if (ep == 0) {
        float w0 = 1.0f / (float)(c0 > 0 ? c0 : 1);
        float w1 = 1.0f / (float)(c1 > 0 ? c1 : 1);
        ushort4 rt = *(const ushort4*)&root[(size_t)node * 128 + l32 * 4];
        ushort4 o;
        o.x = f2bf(bf2f(rt.x) + sx0 * w0 + sx1 * w1);
        o.y = f2bf(bf2f(rt.y) + sy0 * w0 + sy1 * w1);
        o.z = f2bf(bf2f(rt.z) + sz0 * w0 + sz1 * w1);
        o.w = f2bf(bf2f(rt.w) + sw0 * w0 + sw1 * w1);
        *(ushort4*)&vout[(size_t)node * 128 + l32 * 4] = o;
    }
}

// ---------------- batchnorm on combined v ----------------

__global__ __launch_bounds__(256) void k_bnstats(const ushort* __restrict__ v0buf, const ushort* __restrict__ v1buf,
                                                 float* __restrict__ part, int C, int M) {
    int br = blockIdx.y;
    const ushort* v = br ? v1buf : v0buf;
    float* P = part + (size_t)br * 2 * C * BNG;
    int tid = threadIdx.x;
    int half = C >> 1;
    int groups = 256 / half;
    int col2 = tid & (half - 1);
    int rg = tid / half;
    float sx = 0.f, sy = 0.f, qx = 0.f, qy = 0.f;
    for (int row = blockIdx.x * groups + rg; row < M; row += BNG * groups) {
        uint rv = *(const uint*)&v[(size_t)row * C + col2 * 2];
        float v0 = bf2f((ushort)(rv & 0xffff));
        float v1 = bf2f((ushort)(rv >> 16));
        sx += v0; qx += v0 * v0;
        sy += v1; qy += v1 * v1;
    }
    __shared__ float4 sh[256];
    sh[tid] = make_float4(sx, sy, qx, qy);
    __syncthreads();
    if (tid < half) {
        float4 a = sh[tid];
        for (int g = 1; g < groups; g++) {
            float4 b = sh[tid + g * half];
            a.x += b.x; a.y += b.y; a.z += b.z; a.w += b.w;
        }
        int c0 = tid * 2;
        P[(size_t)c0 * BNG + blockIdx.x] = a.x;
        P[(size_t)(c0 + 1) * BNG + blockIdx.x] = a.y;
        P[(size_t)(C + c0) * BNG + blockIdx.x] = a.z;
        P[(size_t)(C + c0 + 1) * BNG + blockIdx.x] = a.w;
    }
}

__global__ __launch_bounds__(256) void k_bnreduce(const float* __restrict__ part,
                                                  const float* __restrict__ g0, const float* __restrict__ be0,
                                                  const float* __restrict__ g1, const float* __restrict__ be1,
                                                  float* __restrict__ ss, int C, float invM) {
    int br = blockIdx.y;
    const float* P = part + (size_t)br * 2 * C * BNG;
    const float* g = br ? g1 : g0;
    const float* be = br ? be1 : be0;
    float* S = ss + br * 2 * C;
    int wv = threadIdx.x >> 6, lane = threadIdx.x & 63;
    int c = blockIdx.x * 4 + wv;
    if (c >= C) return;
    float s = P[(size_t)c * BNG + lane] + P[(size_t)c * BNG + 64 + lane];
    float s2 = P[(size_t)(C + c) * BNG + lane] + P[(size_t)(C + c) * BNG + 64 + lane];
#pragma unroll
    for (int o = 32; o >= 1; o >>= 1) {
        s += __shfl_xor(s, o, 64);
        s2 += __shfl_xor(s2, o, 64);
    }
    if (lane == 0) {
        float mu = s * invM;
        float var = s2 * invM - mu * mu;
        float sc = g[c] * rsqrtf(var + 1e-5f);
        S[c] = sc;
        S[C + c] = be[c] - mu * sc;
    }
}

__global__ __launch_bounds__(256) void k_bnapply(const ushort* __restrict__ v0buf, const ushort* __restrict__ v1buf,
                                                 const float* __restrict__ ss, int C, int M,
                                                 ushort* __restrict__ ob0, ushort* __restrict__ ob1) {
    int br = blockIdx.y;
    const ushort* v = br ? v1buf : v0buf;
    const float* S = ss + br * 2 * C;
    int i = blockIdx.x * 256 + threadIdx.x;
    int total4 = M * C / 4;
    if (i >= total4) return;
    ushort4 vv = *(const ushort4*)&v[(size_t)i * 4];
    int c0 = (i * 4) & (C - 1);
    float y0 = bf2f(vv.x) * S[c0 + 0] + S[C + c0 + 0];
    float y1 = bf2f(vv.y) * S[c0 + 1] + S[C + c0 + 1];
    float y2 = bf2f(vv.z) * S[c0 + 2] + S[C + c0 + 2];
    float y3 = bf2f(vv.w) * S[c0 + 3] + S[C + c0 + 3];
    y0 = y0 >= 0.f ? y0 : 0.01f * y0;
    y1 = y1 >= 0.f ? y1 : 0.01f * y1;
    y2 = y2 >= 0.f ? y2 : 0.01f * y2;
    y3 = y3 >= 0.f ? y3 : 0.01f * y3;
    ushort* ob = br ? ob1 : ob0;
    ushort4 o;
    o.x = f2bf(y0); o.y = f2bf(y1); o.z = f2bf(y2); o.w = f2bf(y3);
    *(ushort4*)&ob[(size_t)i * 4] = o;
}

// ---------------- pooling with fused layer-2 BN+leaky ----------------

__global__ __launch_bounds__(512) void k_pool2(const ushort* __restrict__ v2t, const ushort* __restrict__ v2p,
                                               const int* __restrict__ bt, const int* __restrict__ bp,
                                               const float* __restrict__ ss, float* __restrict__ out) {
    int blk = blockIdx.x;
    int br = blk >> 6, b = blk & 63;
    const ushort* v = br ? v2p : v2t;
    const int* bat = br ? bp : bt;
    const float* S = ss + br * 2 * 128;
    __shared__ int se[2];
    if (threadIdx.x < 2) {
        int val = b + (int)threadIdx.x;
        int lo = 0, hi = NN;
        while (lo < hi) {
            int mid = (lo + hi) >> 1;
            if (bat[mid] < val) lo = mid + 1; else hi = mid;
        }
        se[threadIdx.x] = lo;
    }
    __syncthreads();
    int s = se[0], e = se[1];
    int t2 = threadIdx.x & 63, rg = threadIdx.x >> 6;
    float sc0 = S[t2 * 2], sh0 = S[128 + t2 * 2];
    float sc1 = S[t2 * 2 + 1], sh1 = S[128 + t2 * 2 + 1];
    float ax = 0.f, ay = 0.f;
    for (int r = s + rg; r < e; r += 8) {
        uint rv = *(const uint*)&v[(size_t)r * 128 + t2 * 2];
        float v0 = bf2f((ushort)(rv & 0xffff)) * sc0 + sh0;
        float v1 = bf2f((ushort)(rv >> 16)) * sc1 + sh1;
        v0 = v0 >= 0.f ? v0 : 0.01f * v0;
        v1 = v1 >= 0.f ? v1 : 0.01f * v1;
        ax += v0; ay += v1;
    }
    __shared__ float2 sh[512];
    sh[threadIdx.x] = make_float2(ax, ay);
    __syncthreads();
    if (rg == 0) {
        float2 a = sh[t2];
#pragma unroll
        for (int g = 1; g < 8; g++) {
            float2 vv = sh[t2 + g * 64];
            a.x += vv.x; a.y += vv.y;
        }
        int cnt = e - s;
        float inv = 1.0f / (float)(cnt > 0 ? cnt : 1);
        out[(br * 64 + b) * 128 + t2 * 2] = a.x * inv;
        out[(br * 64 + b) * 128 + t2 * 2 + 1] = a.y * inv;
    }
}

// ---------------- host orchestration ----------------

extern "C" void kernel_launch(void* const* d_in, const int* in_sizes, int n_in,
                              void* d_out, int out_size, void* d_ws, size_t ws_size,
                              hipStream_t stream) {
    const float* x_t = (const float*)d_in[0];
    const float* x_p = (const float*)d_in[1];
    const int* ei_t = (const int*)d_in[2];
    const int* et_t = (const int*)d_in[3];
    const int* bat_t = (const int*)d_in[4];
    const int* ei_p = (const int*)d_in[5];
    const int* et_p = (const int*)d_in[6];
    const int* bat_p = (const int*)d_in[7];
    const float* w_t1_rel = (const float*)d_in[8];
    const float* w_t1_root = (const float*)d_in[9];
    const float* b_t1 = (const float*)d_in[10];
    const float* w_t2_rel = (const float*)d_in[11];
    const float* w_t2_root = (const float*)d_in[12];
    const float* b_t2 = (const float*)d_in[13];
    const float* w_p1_rel = (const float*)d_in[14];
    const float* w_p1_root = (const float*)d_in[15];
    const float* b_p1 = (const float*)d_in[16];
    const float* w_p2_rel = (const float*)d_in[17];
    const float* w_p2_root = (const float*)d_in[18];
    const float* b_p2 = (const float*)d_in[19];
    const float* g_t1 = (const float*)d_in[20]; const float* be_t1 = (const float*)d_in[21];
    const float* g_t2 = (const float*)d_in[22]; const float* be_t2 = (const float*)d_in[23];
    const float* g_p1 = (const float*)d_in[24]; const float* be_p1 = (const float*)d_in[25];
    const float* g_p2 = (const float*)d_in[26]; const float* be_p2 = (const float*)d_in[27];

    char* wp = (char*)d_ws;
    auto alloc = [&](size_t b) -> void* {
        void* p = (void*)wp;
        wp += (b + 255) & ~(size_t)255;
        return p;
    };

    const bool MERGED = ws_size >= (size_t)137 * 1000 * 1000;

    dim3 blk(256);
    const int EB2 = (2 * NE) / 256;          // 2500
    const int SCB2 = (2 * NN + 255) / 256;
    const int nMT = (NN + 127) / 128;

    ushort* xt_bf; ushort* xp_bf;
    ushort *h0t1, *h1t1, *h0p1, *h1p1;
    ushort *root1t, *v1t, *root1p, *v1p;
    ushort *a1t, *a1p;
    ushort *root2t, *v2t, *root2p, *v2p;
    ushort *h0t2, *h1t2, *h0p2, *h1p2;
    ushort* wtb; int* adj; int* posArr; int* off; int* deg; int* csum;
    float* part; float* ss;

    if (MERGED) {
        xt_bf = (ushort*)alloc((size_t)NN * 768 * 2);
        xp_bf = (ushort*)alloc((size_t)NN * 128 * 2);
        h0t1 = (ushort*)alloc((size_t)NN * 256 * 2);
        h1t1 = (ushort*)alloc((size_t)NN * 256 * 2);
        h0p1 = (ushort*)alloc((size_t)NN * 256 * 2);
        h1p1 = (ushort*)alloc((size_t)NN * 256 * 2);
        root1t = (ushort*)alloc((size_t)NN * 256 * 2);
        v1t = (ushort*)alloc((size_t)NN * 256 * 2);
        root1p = (ushort*)alloc((size_t)NN * 256 * 2);
        v1p = (ushort*)alloc((size_t)NN * 256 * 2);
        a1t = (ushort*)alloc((size_t)NN * 256 * 2);
        wtb = (ushort*)alloc((size_t)(3 * 768 * 256 + 3 * 128 * 256 + 2 * 3 * 256 * 128) * 2);
        adj = (int*)alloc((size_t)2 * NE * 4);
        posArr = (int*)alloc((size_t)2 * NE * 4);
        off = (int*)alloc((size_t)(2 * NN + 1) * 4);
        deg = (int*)alloc((size_t)2 * NN * 4);
        csum = (int*)alloc(256 * 4);
        part = (float*)alloc((size_t)2 * 2 * 256 * BNG * 4);
        ss = (float*)alloc(1024 * 4);
        root2t = xt_bf;
        v2t = root2t + (size_t)NN * 128;
        root2p = v2t + (size_t)NN * 128;
        v2p = root2p + (size_t)NN * 128;
        a1p = v2p + (size_t)NN * 128;
        h0t2 = h0t1;                       h0p2 = h0t1 + (size_t)NN * 128;
        h1t2 = h1t1;                       h1p2 = h1t1 + (size_t)NN * 128;
    } else {
        xt_bf = (ushort*)alloc((size_t)NN * 768 * 2);
        xp_bf = (ushort*)alloc((size_t)NN * 128 * 2);
        ushort* h0b = (ushort*)alloc((size_t)NN * 256 * 2);
        ushort* h1b = (ushort*)alloc((size_t)NN * 256 * 2);
        ushort* root1 = (ushort*)alloc((size_t)NN * 256 * 2);
        ushort* v1 = (ushort*)alloc((size_t)NN * 256 * 2);
        a1t = (ushort*)alloc((size_t)NN * 256 * 2);
        wtb = (ushort*)alloc((size_t)(3 * 768 * 256 + 3 * 128 * 256 + 2 * 3 * 256 * 128) * 2);
        adj = (int*)alloc((size_t)2 * NE * 4);
        posArr = (int*)alloc((size_t)2 * NE * 4);
        off = (int*)alloc((size_t)(2 * NN + 1) * 4);
        deg = (int*)alloc((size_t)2 * NN * 4);
        csum = (int*)alloc(256 * 4);
        part = (float*)alloc((size_t)2 * 2 * 256 * BNG * 4);
        ss = (float*)alloc(1024 * 4);
        h0t1 = h0b; h1t1 = h1b; h0p1 = h0b; h1p1 = h1b;
        root1t = root1; v1t = v1; root1p = root1; v1p = v1;
        root2t = xt_bf;
        v2t = root2t + (size_t)NN * 128;
        root2p = v2t + (size_t)NN * 128;
        v2p = root2p + (size_t)NN * 128;
        a1p = v2p + (size_t)NN * 128;
        h0t2 = h0b;                        h0p2 = h0b + (size_t)NN * 128;
        h1t2 = h1b;                        h1p2 = h1b + (size_t)NN * 128;
    }

    ushort* wt_t1 = wtb;
    ushort* wt_p1 = wt_t1 + 3 * 768 * 256;
    ushort* wt_t2 = wt_p1 + 3 * 128 * 256;
    ushort* wt_p2 = wt_t2 + 3 * 256 * 128;
    WtJob j0 = {w_t1_root, w_t1_rel, wt_t1, 768, 256};
    WtJob j1 = {w_p1_root, w_p1_rel, wt_p1, 128, 256};
    WtJob j2 = {w_t2_root, w_t2_rel, wt_t2, 256, 128};
    WtJob j3 = {w_p2_root, w_p2_rel, wt_p2, 256, 128};

    int n4t = NN * 768 / 4, n4p = NN * 128 / 4;
    int nbCast = (n4t + n4p + 255) / 256;

    // ---- fused prep: countpos ∥ cast_x ∥ cast_wt ----
    hipMemsetAsync(deg, 0, (size_t)2 * NN * 4, stream);
    k_prep<<<EB2 + nbCast + 864, blk, 0, stream>>>(ei_t, ei_p, deg, posArr,
                                                   x_t, x_p, xt_bf, xp_bf, n4t, n4p,
                                                   j0, j1, j2, j3, 576, 672, 768, EB2, nbCast);
    k_scan_local<<<SCB2, blk, 0, stream>>>(deg, off, csum, 2 * NN);
    k_scan_csum<<<1, 256, 0, stream>>>(csum, off + 2 * NN, SCB2);
    k_scan_add<<<SCB2, blk, 0, stream>>>(off, csum, 2 * NN);

    FillArgs fa = {ei_t, et_t, ei_p, et_p, off, posArr, adj};
    GemmJob Gt1 = {xt_bf, wt_t1, b_t1, root1t, h0t1, h1t1, 768};
    GemmJob Gp1 = {xp_bf, wt_p1, b_p1, root1p, h0p1, h1p1, 128};

    if (MERGED) {
        int nwgG = nMT * 4 * 2;  // 1256
        k_gemm_fill<<<nwgG + EB2, blk, 0, stream>>>(Gt1, Gp1, NN, 256, 2, nwgG, fa);
        k_agg256<<<NN, blk, 0, stream>>>(off, adj, h0t1, h1t1, root1t, v1t,
                                         h0p1, h1p1, root1p, v1p, NN / 2);
        k_bnstats<<<dim3(BNG, 2), blk, 0, stream>>>(v1t, v1p, part, 256, NN);
        k_bnreduce<<<dim3(64, 2), blk, 0, stream>>>(part, g_t1, be_t1, g_p1, be_p1, ss, 256, 1.0f / NN);
        k_bnapply<<<dim3((NN * 256 / 4 + 255) / 256, 2), blk, 0, stream>>>(
            v1t, v1p, ss, 256, NN, a1t, a1p);
    } else {
        int nwgG = nMT * 4;
        k_gemm_fill<<<nwgG + EB2, blk, 0, stream>>>(Gt1, Gt1, NN, 256, 1, nwgG, fa);
        k_agg256<<<NN / 2, blk, 0, stream>>>(off, adj, h0t1, h1t1, root1t, v1t,
                                             h0t1, h1t1, root1t, v1t, NN / 2);
        k_bnstats<<<dim3(BNG, 1), blk, 0, stream>>>(v1t, v1t, part, 256, NN);
        k_bnreduce<<<dim3(64, 1), blk, 0, stream>>>(part, g_t1, be_t1, g_t1, be_t1, ss, 256, 1.0f / NN);
        k_bnapply<<<dim3((NN * 256 / 4 + 255) / 256, 1), blk, 0, stream>>>(
            v1t, v1t, ss, 256, NN, a1t, a1t);

        k_gemm_fill<<<nwgG, blk, 0, stream>>>(Gp1, Gp1, NN, 256, 1, nwgG, fa);
        k_agg256<<<NN / 2, blk, 0, stream>>>(off + NN, adj, h0p1, h1p1, root1p, v1p,
                                             h0p1, h1p1, root1p, v1p, NN / 2);
        k_bnstats<<<dim3(BNG, 1), blk, 0, stream>>>(v1p, v1p, part, 256, NN);
        k_bnreduce<<<dim3(64, 1), blk, 0, stream>>>(part, g_p1, be_p1, g_p1, be_p1, ss, 256, 1.0f / NN);
        k_bnapply<<<dim3((NN * 256 / 4 + 255) / 256, 1), blk, 0, stream>>>(
            v1p, v1p, ss, 256, NN, a1p, a1p);
    }

    // ---- layer 2, both branches merged ----
    GemmJob Gt2 = {a1t, wt_t2, b_t2, root2t, h0t2, h1t2, 256};
    GemmJob Gp2 = {a1p, wt_p2, b_p2, root2p, h0p2, h1p2, 256};
    int nwg2 = nMT * 2 * 2;  // 628
    k_gemm_fill<<<nwg2, blk, 0, stream>>>(Gt2, Gp2, NN, 128, 2, nwg2, fa);
    k_agg128<<<2 * (NN / 4), blk, 0, stream>>>(off, adj, h0t2, h1t2, root2t, v2t,
                                               h0p2, h1p2, root2p, v2p);
    k_bnstats<<<dim3(BNG, 2), blk, 0, stream>>>(v2t, v2p, part, 128, NN);
    k_bnreduce<<<dim3(32, 2), blk, 0, stream>>>(part, g_t2, be_t2, g_p2, be_p2, ss, 128, 1.0f / NN);

    // ---- pool both ----
    k_pool2<<<128, 512, 0, stream>>>(v2t, v2p, bat_t, bat_p, ss, (float*)d_out);
}